// Round 13
// baseline (167.280 us; speedup 1.0000x reference)
//
#include <hip/hip_runtime.h>
#include <hip/hip_bf16.h>

typedef __bf16 bf16x8 __attribute__((ext_vector_type(8)));
typedef float  f32x4  __attribute__((ext_vector_type(4)));

// Sizes: q [1024][128] f32, k [1024][128] f32, queue [128][65536] f32,
//        prototypes [1000][128] f32, target [1024] int32
// Outputs (concat f32): logits [1024][65537], logits_proto [1024][1000],
//        new_queue [128][65536], new_prototypes [1000][128]
// d_ws: Bt = bf16 queue^T [65536][128], qbf = bf16(10*q) [1024][128]
// R13 = R12 with the gemm tile widened to 64x512 (512 thr, 8 waves):
//      each block writes 2KB contiguous PER LOGITS ROW within one epilogue
//      window -> L2 can assemble full DRAM pages (R12's 512B spans = ~40%
//      page efficiency, the measured 2.8TB/s drain). Only untested write lever.

#define B_   1024
#define D_   128
#define K_   65536
#define C_   1000
#define LROW 65537
#define TINV 10.0f

// ---- bt_make: queue col-tiles -> bf16 transposed Bt ----
__global__ __launch_bounds__(256) void bt_make(const float* __restrict__ queue,
                                               __bf16* __restrict__ Bt) {
    __shared__ __bf16 Lt[128 * 128];
    char* ltb = (char*)Lt;
    const int tid = threadIdx.x;
    const int c0  = blockIdx.x * 128;
    #pragma unroll
    for (int it = 0; it < 16; ++it) {
        const int idx = it * 256 + tid;          // float4 slot in 128d x 128c tile
        const int d   = idx >> 5;
        const int cq  = (idx & 31) * 4;
        const f32x4 v = *reinterpret_cast<const f32x4*>(queue + (size_t)d * K_ + c0 + cq);
        const int db = d >> 3, de = (d & 7) * 2;
        #pragma unroll
        for (int jj = 0; jj < 4; ++jj) {
            const int c = cq + jj;
            *reinterpret_cast<__bf16*>(ltb + c * 256 + ((db ^ ((c >> 2) & 15)) << 4) + de)
                = (__bf16)v[jj];
        }
    }
    __syncthreads();
    #pragma unroll
    for (int it = 0; it < 8; ++it) {
        const int idx = it * 256 + tid;          // 16B chunk: c = idx>>4, db = idx&15
        const int c   = idx >> 4;
        const int db  = idx & 15;
        const bf16x8 v = *reinterpret_cast<const bf16x8*>(
            ltb + c * 256 + ((db ^ ((c >> 2) & 15)) << 4));
        *reinterpret_cast<bf16x8*>(Bt + (size_t)(c0 + c) * D_ + db * 8) = v;
    }
}

// ---- misc_fused: lpos+qbf | gemm_proto | proto_update ----
#define MB_LPOS   256
#define MB_PROTO  1008   // (63,16) linearized
#define MB_PUPD   500    // 2 classes per block
__global__ __launch_bounds__(256) void misc_fused(const float* __restrict__ q,
                                                  const float* __restrict__ k,
                                                  const float* __restrict__ protos,
                                                  const int* __restrict__ target,
                                                  float* __restrict__ logits,
                                                  __bf16* __restrict__ qbf,
                                                  float* __restrict__ lproto,
                                                  float* __restrict__ outp) {
    __shared__ int   t[B_];
    __shared__ float red[2][2];
    const int bid = blockIdx.x;
    const int tid = threadIdx.x;

    if (bid < MB_LPOS) {
        // ---- l_pos + qbf ----
        const int wid  = tid >> 6;
        const int lane = tid & 63;
        const int row  = bid * 4 + wid;
        const float2 qv = reinterpret_cast<const float2*>(q + (size_t)row * D_)[lane];
        const float2 kv = reinterpret_cast<const float2*>(k + (size_t)row * D_)[lane];
        union { __bf16 h[2]; unsigned int u; } u2;
        u2.h[0] = (__bf16)(qv.x * TINV);
        u2.h[1] = (__bf16)(qv.y * TINV);
        reinterpret_cast<unsigned int*>(qbf)[row * 64 + lane] = u2.u;
        float p = qv.x * kv.x + qv.y * kv.y;
        #pragma unroll
        for (int off = 32; off > 0; off >>= 1) p += __shfl_xor(p, off);
        if (lane == 0) logits[(size_t)row * LROW] = p * TINV;

    } else if (bid < MB_LPOS + MB_PROTO) {
        // ---- gemm_proto: lproto = (10*q) @ protos^T ----
        const int pid  = bid - MB_LPOS;
        const int bx   = pid % 63, by = pid / 63;
        const int wid  = tid >> 6;
        const int lane = tid & 63;
        const int mrow = (by * 4 + wid) * 16;
        const int ncol = bx * 16;
        const int bl = lane & 15, gk = lane >> 4;
        const int col = ncol + bl;
        const bool valid = (col < C_);

        f32x4 acc = {};
        #pragma unroll
        for (int s = 0; s < 4; ++s) {
            const int koff = s * 32 + gk * 8;
            const float* ap = q + (size_t)(mrow + bl) * D_ + koff;
            bf16x8 a, b;
            #pragma unroll
            for (int v = 0; v < 8; ++v) a[v] = (__bf16)(ap[v] * TINV);
            if (valid) {
                const float* bp = protos + (size_t)col * D_ + koff;
                #pragma unroll
                for (int v = 0; v < 8; ++v) b[v] = (__bf16)bp[v];
            } else {
                #pragma unroll
                for (int v = 0; v < 8; ++v) b[v] = (__bf16)0.0f;
            }
            acc = __builtin_amdgcn_mfma_f32_16x16x32_bf16(a, b, acc, 0, 0, 0);
        }
        #pragma unroll
        for (int r = 0; r < 4; ++r) {
            const int orow = mrow + gk * 4 + r;
            if (valid) lproto[(size_t)orow * C_ + col] = acc[r];
        }

    } else {
        // ---- proto_update: 2 classes per block ----
        const int pid = bid - (MB_LPOS + MB_PROTO);
        const int sub = tid >> 7;          // 0/1
        const int d   = tid & 127;
        const int c   = pid * 2 + sub;     // < 1000
        for (int i = tid; i < B_; i += 256) t[i] = target[i];
        __syncthreads();

        float acc = 0.0f, wgt = 1.0f;
        int cnt = 0;
        for (int i = 0; i < B_; ++i) {
            if (t[i] == c) {                 // wave-uniform (LDS broadcast)
                ++cnt;
                wgt *= 1.0010010010010010f;  // 1/0.999 -> m^(-occ_i)
                acc = fmaf(wgt, q[(size_t)i * D_ + d], acc);
            }
        }
        const float val = powf(0.999f, (float)cnt) *
                          fmaf(0.001f, acc, protos[(size_t)c * D_ + d]);

        float ss = val * val;
        #pragma unroll
        for (int off = 32; off > 0; off >>= 1) ss += __shfl_xor(ss, off);
        if ((d & 63) == 0) red[sub][d >> 6] = ss;
        __syncthreads();
        const float norm = sqrtf(red[sub][0] + red[sub][1]);
        outp[(size_t)c * D_ + d] = val / fmaxf(norm, 1e-12f);
    }
}

// ---- mega (512 thr): qcopy blocks [0,256) || gemm 64x512-tile blocks [256,2304) ----
__global__ __launch_bounds__(512) void mega(const __bf16* __restrict__ qbf,
                                            const __bf16* __restrict__ Bt,
                                            const float* __restrict__ queue,
                                            const float* __restrict__ k,
                                            float* __restrict__ logits,
                                            float* __restrict__ outq) {
    __shared__ __bf16 Alds[64][128];
    const int tid = threadIdx.x;

    if (blockIdx.x < 256) {
        // ---- qcopy: new_queue row-half per block; cols<1024 = k^T ----
        const int d    = blockIdx.x >> 1;
        const int half = blockIdx.x & 1;
        const size_t rowoff = (size_t)d * K_;
        const f32x4* src = reinterpret_cast<const f32x4*>(queue + rowoff);
        f32x4*       dst = reinterpret_cast<f32x4*>(outq + rowoff);
        if (half == 0) {
            #pragma unroll
            for (int i = 0; i < 2; ++i) {             // cols 0..1023 from k^T
                const int c = i * 512 + tid;
                outq[rowoff + c] = k[(size_t)c * D_ + d];
            }
            #pragma unroll 4
            for (int i = 0; i < 16; ++i) {            // float4 idx 256..8191
                const int idx = 256 + i * 512 + tid;
                if (idx < 8192) dst[idx] = src[idx];
            }
        } else {
            #pragma unroll 4
            for (int i = 0; i < 16; ++i) {            // float4 idx 8192..16383
                const int idx = 8192 + i * 512 + tid;
                dst[idx] = src[idx];
            }
        }
        return;
    }

    // ---- gemm: 64 rows x 512 cols per block; wave w owns 64-col strip ----
    const int wid = tid >> 6, lane = tid & 63;
    const int lin = blockIdx.x - 256;                // 0..2047
    const int xcd = lin & 7, j = lin >> 3;           // j: 0..255
    const int ctile = xcd * 16 + (j >> 4);           // 0..127 (512-col tiles)
    const int rtile = j & 15;                        // 0..15
    const int bcol = ctile * 512;
    const int brow = rtile * 64;

    #pragma unroll
    for (int it = 0; it < 2; ++it) {
        const int idx = it * 512 + tid;          // 16B-block slot 0..1023
        const int r   = idx >> 4;                // 0..63
        const int cb  = idx & 15;
        const bf16x8 v = *reinterpret_cast<const bf16x8*>(qbf + (size_t)(brow + r) * D_ + cb * 8);
        *reinterpret_cast<bf16x8*>(&Alds[r][(cb ^ (r & 7)) * 8]) = v;
    }
    __syncthreads();

    const int bl = lane & 15, gk = lane >> 4;
    const int colbase = bcol + wid * 64;

    f32x4 acc[4][4] = {};
    #pragma unroll
    for (int s = 0; s < 4; ++s) {
        const int koff = s * 32 + gk * 8;
        bf16x8 af[4];
        #pragma unroll
        for (int m = 0; m < 4; ++m) {
            const int r = m * 16 + bl;
            af[m] = *reinterpret_cast<const bf16x8*>(&Alds[r][((s * 4 + gk) ^ (r & 7)) * 8]);
        }
        #pragma unroll
        for (int n = 0; n < 4; ++n) {
            const bf16x8 bfrag = *reinterpret_cast<const bf16x8*>(
                Bt + (size_t)(colbase + n * 16 + bl) * D_ + koff);
            #pragma unroll
            for (int m = 0; m < 4; ++m)
                acc[m][n] = __builtin_amdgcn_mfma_f32_16x16x32_bf16(af[m], bfrag, acc[m][n], 0, 0, 0);
        }
    }

    // C/D: col = lane&15, row = (lane>>4)*4 + r; 8 waves together cover a
    // 2KB span per row within one epilogue window -> L2 page assembly.
    #pragma unroll
    for (int m = 0; m < 4; ++m)
        #pragma unroll
        for (int n = 0; n < 4; ++n)
            #pragma unroll
            for (int r = 0; r < 4; ++r) {
                const int orow = brow + m * 16 + (gk << 2) + r;
                logits[(size_t)orow * LROW + 1 + colbase + n * 16 + bl] = acc[m][n][r];
            }
}

extern "C" void kernel_launch(void* const* d_in, const int* in_sizes, int n_in,
                              void* d_out, int out_size, void* d_ws, size_t ws_size,
                              hipStream_t stream) {
    const float* q      = (const float*)d_in[0];
    const float* k      = (const float*)d_in[1];
    const float* queue  = (const float*)d_in[2];
    const float* protos = (const float*)d_in[3];
    const int*   target = (const int*)d_in[4];

    float* out    = (float*)d_out;
    float* logits = out;                                  // [1024][65537]
    float* lproto = out + (size_t)B_ * LROW;              // [1024][1000]
    float* outq   = lproto + (size_t)B_ * C_;             // [128][65536]
    float* outp   = outq + (size_t)D_ * K_;               // [1000][128]

    __bf16* Bt  = (__bf16*)d_ws;                          // [65536][128]
    __bf16* qbf = (__bf16*)((char*)d_ws + (size_t)K_ * D_ * 2);  // [1024][128]

    bt_make   <<<K_ / 128, 256, 0, stream>>>(queue, Bt);
    misc_fused<<<MB_LPOS + MB_PROTO + MB_PUPD, 256, 0, stream>>>(
        q, k, protos, target, logits, qbf, lproto, outp);
    mega      <<<256 + 2048, 512, 0, stream>>>(qbf, Bt, queue, k, logits, outq);
}

// Round 14
// 97.999 us; speedup vs baseline: 1.7070x; 1.7070x over previous
//
#include <hip/hip_runtime.h>
#include <hip/hip_bf16.h>

typedef __bf16 bf16x8 __attribute__((ext_vector_type(8)));
typedef float  f32x4  __attribute__((ext_vector_type(4)));

// Sizes: q [1024][128] f32, k [1024][128] f32, queue [128][65536] f32,
//        prototypes [1000][128] f32, target [1024] int32
// Outputs (concat f32): logits [1024][65537], logits_proto [1024][1000],
//        new_queue [128][65536], new_prototypes [1000][128]
// d_ws: Bt = bf16 queue^T [65536][128], qbf = bf16(10*q) [1024][128]
// R14 = R12 (measured best 155.4us) with the serial prefix minimized:
//   prep = bt_make + lpos/qbf (the only true mega dependencies), 1 launch
//   mega = qcopy | gemm_proto | proto_update | gemm  (indep. roles ride inside
//          the write-drain-bound gemm window). 2 launches total (was 3).
// Write-side ledger (R4/R6/R8/R9/R10/R13 all neutral-or-worse): 268MB logits
// at ~2.8TB/s is intrinsic to the +4B-misaligned 256KB-row layout. T(gemm64)~97us.

#define B_   1024
#define D_   128
#define K_   65536
#define C_   1000
#define LROW 65537
#define TINV 10.0f

// ---- prep: bt_make blocks [0,512) | lpos+qbf blocks [512,768) ----
__global__ __launch_bounds__(256) void prep(const float* __restrict__ queue,
                                            const float* __restrict__ q,
                                            const float* __restrict__ k,
                                            __bf16* __restrict__ Bt,
                                            __bf16* __restrict__ qbf,
                                            float* __restrict__ logits) {
    __shared__ __bf16 Lt[128 * 128];
    const int tid = threadIdx.x;

    if (blockIdx.x < 512) {
        // ---- bt_make: queue col-tile -> bf16 transposed Bt ----
        char* ltb = (char*)Lt;
        const int c0 = blockIdx.x * 128;
        #pragma unroll
        for (int it = 0; it < 16; ++it) {
            const int idx = it * 256 + tid;          // float4 slot in 128d x 128c tile
            const int d   = idx >> 5;
            const int cq  = (idx & 31) * 4;
            const f32x4 v = *reinterpret_cast<const f32x4*>(queue + (size_t)d * K_ + c0 + cq);
            const int db = d >> 3, de = (d & 7) * 2;
            #pragma unroll
            for (int jj = 0; jj < 4; ++jj) {
                const int c = cq + jj;
                *reinterpret_cast<__bf16*>(ltb + c * 256 + ((db ^ ((c >> 2) & 15)) << 4) + de)
                    = (__bf16)v[jj];
            }
        }
        __syncthreads();
        #pragma unroll
        for (int it = 0; it < 8; ++it) {
            const int idx = it * 256 + tid;          // 16B chunk: c = idx>>4, db = idx&15
            const int c   = idx >> 4;
            const int db  = idx & 15;
            const bf16x8 v = *reinterpret_cast<const bf16x8*>(
                ltb + c * 256 + ((db ^ ((c >> 2) & 15)) << 4));
            *reinterpret_cast<bf16x8*>(Bt + (size_t)(c0 + c) * D_ + db * 8) = v;
        }
    } else {
        // ---- l_pos + qbf ----
        const int wid  = tid >> 6;
        const int lane = tid & 63;
        const int row  = (blockIdx.x - 512) * 4 + wid;
        const float2 qv = reinterpret_cast<const float2*>(q + (size_t)row * D_)[lane];
        const float2 kv = reinterpret_cast<const float2*>(k + (size_t)row * D_)[lane];
        union { __bf16 h[2]; unsigned int u; } u2;
        u2.h[0] = (__bf16)(qv.x * TINV);
        u2.h[1] = (__bf16)(qv.y * TINV);
        reinterpret_cast<unsigned int*>(qbf)[row * 64 + lane] = u2.u;
        float p = qv.x * kv.x + qv.y * kv.y;
        #pragma unroll
        for (int off = 32; off > 0; off >>= 1) p += __shfl_xor(p, off);
        if (lane == 0) logits[(size_t)row * LROW] = p * TINV;
    }
}

// ---- mega: qcopy [0,512) | gemm_proto [512,1520) | proto_update [1520,2020)
//            | gemm [2020, 10212). 256 threads. 16KB shared LDS arena. ----
#define MG_QCOPY 512
#define MG_PROTO 1008
#define MG_PUPD  500
#define MG_PRE   (MG_QCOPY + MG_PROTO + MG_PUPD)   // 2020
__global__ __launch_bounds__(256) void mega(const __bf16* __restrict__ qbf,
                                            const __bf16* __restrict__ Bt,
                                            const float* __restrict__ queue,
                                            const float* __restrict__ k,
                                            const float* __restrict__ q,
                                            const float* __restrict__ protos,
                                            const int* __restrict__ target,
                                            float* __restrict__ logits,
                                            float* __restrict__ lproto,
                                            float* __restrict__ outq,
                                            float* __restrict__ outp) {
    __shared__ char smem[16384];
    const int tid = threadIdx.x;
    const int bid = blockIdx.x;

    if (bid < MG_QCOPY) {
        // ---- qcopy: new_queue = queue in linear spans; cols<1024 = k^T ----
        const int d  = bid >> 2;
        const int qt = bid & 3;
        const size_t rowoff = (size_t)d * K_;
        const f32x4* src = reinterpret_cast<const f32x4*>(queue + rowoff);
        f32x4*       dst = reinterpret_cast<f32x4*>(outq + rowoff);
        if (qt == 0) {
            #pragma unroll
            for (int i = 0; i < 4; ++i) {            // cols 0..1023 from k^T
                const int c = i * 256 + tid;
                outq[rowoff + c] = k[(size_t)c * D_ + d];
            }
            #pragma unroll 4
            for (int i = 0; i < 15; ++i) {
                const int idx = 256 + i * 256 + tid; // float4 index
                dst[idx] = src[idx];
            }
        } else {
            const int base = qt * 4096;              // float4 index
            #pragma unroll 4
            for (int i = 0; i < 16; ++i) {
                const int idx = base + i * 256 + tid;
                dst[idx] = src[idx];
            }
        }

    } else if (bid < MG_QCOPY + MG_PROTO) {
        // ---- gemm_proto: lproto = (10*q) @ protos^T ----
        const int pid  = bid - MG_QCOPY;
        const int bx   = pid % 63, by = pid / 63;
        const int wid  = tid >> 6;
        const int lane = tid & 63;
        const int mrow = (by * 4 + wid) * 16;
        const int ncol = bx * 16;
        const int bl = lane & 15, gk = lane >> 4;
        const int col = ncol + bl;
        const bool valid = (col < C_);

        f32x4 acc = {};
        #pragma unroll
        for (int s = 0; s < 4; ++s) {
            const int koff = s * 32 + gk * 8;
            const float* ap = q + (size_t)(mrow + bl) * D_ + koff;
            bf16x8 a, b;
            #pragma unroll
            for (int v = 0; v < 8; ++v) a[v] = (__bf16)(ap[v] * TINV);
            if (valid) {
                const float* bp = protos + (size_t)col * D_ + koff;
                #pragma unroll
                for (int v = 0; v < 8; ++v) b[v] = (__bf16)bp[v];
            } else {
                #pragma unroll
                for (int v = 0; v < 8; ++v) b[v] = (__bf16)0.0f;
            }
            acc = __builtin_amdgcn_mfma_f32_16x16x32_bf16(a, b, acc, 0, 0, 0);
        }
        #pragma unroll
        for (int r = 0; r < 4; ++r) {
            const int orow = mrow + gk * 4 + r;
            if (valid) lproto[(size_t)orow * C_ + col] = acc[r];
        }

    } else if (bid < MG_PRE) {
        // ---- proto_update: 2 classes per block ----
        int*   t   = reinterpret_cast<int*>(smem);            // [1024]
        float* red = reinterpret_cast<float*>(smem + 4096);   // [2][2]
        const int pid = bid - (MG_QCOPY + MG_PROTO);
        const int sub = tid >> 7;          // 0/1
        const int d   = tid & 127;
        const int c   = pid * 2 + sub;     // < 1000
        for (int i = tid; i < B_; i += 256) t[i] = target[i];
        __syncthreads();

        float acc = 0.0f, wgt = 1.0f;
        int cnt = 0;
        for (int i = 0; i < B_; ++i) {
            if (t[i] == c) {                 // wave-uniform (LDS broadcast)
                ++cnt;
                wgt *= 1.0010010010010010f;  // 1/0.999 -> m^(-occ_i)
                acc = fmaf(wgt, q[(size_t)i * D_ + d], acc);
            }
        }
        const float val = powf(0.999f, (float)cnt) *
                          fmaf(0.001f, acc, protos[(size_t)c * D_ + d]);

        float ss = val * val;
        #pragma unroll
        for (int off = 32; off > 0; off >>= 1) ss += __shfl_xor(ss, off);
        if ((d & 63) == 0) red[sub * 2 + (d >> 6)] = ss;
        __syncthreads();
        const float norm = sqrtf(red[sub * 2] + red[sub * 2 + 1]);
        outp[(size_t)c * D_ + d] = val / fmaxf(norm, 1e-12f);

    } else {
        // ---- gemm: logits[:,1:] = qbf @ Bt^T, 64x128 tile (R12's config) ----
        __bf16 (*Alds)[128] = reinterpret_cast<__bf16 (*)[128]>(smem);
        const int wid = tid >> 6, lane = tid & 63;
        const int lin = bid - MG_PRE;                    // 0..8191
        const int xcd = lin & 7, j = lin >> 3;           // j: 0..1023
        const int ctile = xcd * 64 + (j >> 4);           // 0..511
        const int rtile = j & 15;                        // 0..15
        const int bcol = ctile * 128;
        const int brow = rtile * 64;

        #pragma unroll
        for (int it = 0; it < 4; ++it) {
            const int idx = it * 256 + tid;          // 16B-block slot 0..1023
            const int r   = idx >> 4;                // 0..63
            const int cb  = idx & 15;
            const bf16x8 v = *reinterpret_cast<const bf16x8*>(qbf + (size_t)(brow + r) * D_ + cb * 8);
            *reinterpret_cast<bf16x8*>(&Alds[r][(cb ^ (r & 7)) * 8]) = v;
        }
        __syncthreads();

        const int bl = lane & 15, gk = lane >> 4;
        const int colbase = bcol + wid * 32;

        f32x4 acc[4][2] = {};
        #pragma unroll
        for (int s = 0; s < 4; ++s) {
            const int koff = s * 32 + gk * 8;
            bf16x8 af[4];
            #pragma unroll
            for (int m = 0; m < 4; ++m) {
                const int r = m * 16 + bl;
                af[m] = *reinterpret_cast<const bf16x8*>(&Alds[r][((s * 4 + gk) ^ (r & 7)) * 8]);
            }
            #pragma unroll
            for (int n = 0; n < 2; ++n) {
                const bf16x8 bfrag = *reinterpret_cast<const bf16x8*>(
                    Bt + (size_t)(colbase + n * 16 + bl) * D_ + koff);
                #pragma unroll
                for (int m = 0; m < 4; ++m)
                    acc[m][n] = __builtin_amdgcn_mfma_f32_16x16x32_bf16(af[m], bfrag, acc[m][n], 0, 0, 0);
            }
        }

        // C/D: col = lane&15, row = (lane>>4)*4 + r
        #pragma unroll
        for (int m = 0; m < 4; ++m)
            #pragma unroll
            for (int n = 0; n < 2; ++n)
                #pragma unroll
                for (int r = 0; r < 4; ++r) {
                    const int orow = brow + m * 16 + (gk << 2) + r;
                    logits[(size_t)orow * LROW + 1 + colbase + n * 16 + bl] = acc[m][n][r];
                }
    }
}

extern "C" void kernel_launch(void* const* d_in, const int* in_sizes, int n_in,
                              void* d_out, int out_size, void* d_ws, size_t ws_size,
                              hipStream_t stream) {
    const float* q      = (const float*)d_in[0];
    const float* k      = (const float*)d_in[1];
    const float* queue  = (const float*)d_in[2];
    const float* protos = (const float*)d_in[3];
    const int*   target = (const int*)d_in[4];

    float* out    = (float*)d_out;
    float* logits = out;                                  // [1024][65537]
    float* lproto = out + (size_t)B_ * LROW;              // [1024][1000]
    float* outq   = lproto + (size_t)B_ * C_;             // [128][65536]
    float* outp   = outq + (size_t)D_ * K_;               // [1000][128]

    __bf16* Bt  = (__bf16*)d_ws;                          // [65536][128]
    __bf16* qbf = (__bf16*)((char*)d_ws + (size_t)K_ * D_ * 2);  // [1024][128]

    prep<<<512 + 256, 256, 0, stream>>>(queue, q, k, Bt, qbf, logits);
    mega<<<MG_PRE + 8192, 256, 0, stream>>>(qbf, Bt, queue, k, q, protos, target,
                                            logits, lproto, outq, outp);
}